// Round 1
// baseline (207.219 us; speedup 1.0000x reference)
//
#include <hip/hip_runtime.h>
#include <hip/hip_bf16.h>
#include <stdint.h>

// ---------------------------------------------------------------------------
// MaskedPolicy: obs->MLP->heads (masked log-softmax, gather, entropy) + critic
// B=8192 OBS=512 HID=1024 N*SUM=2560 (+512 critic cols = 3072 fused GEMM3)
// ---------------------------------------------------------------------------

typedef __bf16 v8bf __attribute__((ext_vector_type(8)));
typedef float  v4f  __attribute__((ext_vector_type(4)));

__device__ __forceinline__ void load_lds16(const void* g, void* l) {
  // CK-style addrspace cast via uintptr (low 32 bits of generic LDS addr = LDS offset)
  auto gp = (const __attribute__((address_space(1))) char*)(uintptr_t)g;
  auto lp = (__attribute__((address_space(3))) char*)(uintptr_t)l;
  __builtin_amdgcn_global_load_lds(gp, lp, 16, 0, 0);
}

// ---------------------------------------------------------------------------
// prep kernels
// ---------------------------------------------------------------------------

__global__ void convert_obs(const float4* __restrict__ in, int4* __restrict__ out, int n8) {
  const int i = blockIdx.x * blockDim.x + threadIdx.x;
  if (i >= n8) return;
  const float4 x = in[i * 2], y = in[i * 2 + 1];
  union { __hip_bfloat16 h[8]; int4 v; } u;
  u.h[0] = __float2bfloat16(x.x);
  u.h[1] = __float2bfloat16(x.y);
  u.h[2] = __float2bfloat16(x.z);
  u.h[3] = __float2bfloat16(x.w);
  u.h[4] = __float2bfloat16(y.x);
  u.h[5] = __float2bfloat16(y.y);
  u.h[6] = __float2bfloat16(y.z);
  u.h[7] = __float2bfloat16(y.w);
  out[i] = u.v;
}

__global__ void build_bias(const float* __restrict__ headsb, const float* __restrict__ bc1,
                           float* __restrict__ biasc) {
  const int i = blockIdx.x * blockDim.x + threadIdx.x;
  if (i < 2560) biasc[i] = headsb[i];
  else if (i < 3072) biasc[i] = bc1[i - 2560];
}

// [R][C] f32  ->  [C][R] bf16   (R,C multiples of 32; batched via z)
__global__ void transpose_to_bf16(const float* __restrict__ in, __hip_bfloat16* __restrict__ out,
                                  int R, int C) {
  __shared__ float t[32][33];
  const int bx = blockIdx.x * 32, by = blockIdx.y * 32;
  in  += (size_t)blockIdx.z * R * C;
  out += (size_t)blockIdx.z * R * C;
  const int x = threadIdx.x, y = threadIdx.y;
#pragma unroll
  for (int i = 0; i < 32; i += 8)
    t[y + i][x] = in[(size_t)(by + y + i) * C + bx + x];
  __syncthreads();
#pragma unroll
  for (int i = 0; i < 32; i += 8)
    out[(size_t)(bx + y + i) * R + by + x] = __float2bfloat16(t[x][y + i]);
}

// ---------------------------------------------------------------------------
// GEMM: C[M][N] = relu?(A[M][K](bf16) * Bt[N][K](bf16)^T + bias[N]) -> bf16
// 128x128 tile, BK=32, 4 waves (2x2), mfma_f32_16x16x32_bf16, global_load_lds,
// bank-conflict-free chunk swizzle c(r,s) = (4r + (s^(r&3))) ^ (r&4).
// ---------------------------------------------------------------------------

__global__ __launch_bounds__(256, 2)
void gemm_bf16_tn(const __hip_bfloat16* __restrict__ A,
                  const __hip_bfloat16* __restrict__ Bt,
                  const float* __restrict__ bias,
                  __hip_bfloat16* __restrict__ C,
                  int M, int N, int K, int relu_from) {
  __shared__ char As[8192];
  __shared__ char Bs[8192];
  const int tid  = threadIdx.x;
  const int lane = tid & 63;
  const int wave = tid >> 6;
  const int wr = wave >> 1, wc = wave & 1;
  const int m0 = blockIdx.y * 128, n0 = blockIdx.x * 128;

  // staging: this thread owns LDS chunks c0 and c1 (16B each); decode to (row, slot)
  const int c0 = tid, c1 = tid + 256;
  const int r0 = ((c0 >> 3) << 1) | (((c0 >> 2) ^ (c0 >> 4)) & 1);
  const int s0 = (c0 & 3) ^ (r0 & 3);
  const int r1 = ((c1 >> 3) << 1) | (((c1 >> 2) ^ (c1 >> 4)) & 1);
  const int s1 = (c1 & 3) ^ (r1 & 3);

  const char* pa0 = (const char*)A  + ((size_t)(m0 + r0) * K) * 2 + s0 * 16;
  const char* pa1 = (const char*)A  + ((size_t)(m0 + r1) * K) * 2 + s1 * 16;
  const char* pb0 = (const char*)Bt + ((size_t)(n0 + r0) * K) * 2 + s0 * 16;
  const char* pb1 = (const char*)Bt + ((size_t)(n0 + r1) * K) * 2 + s1 * 16;

  char* la0 = As + c0 * 16;
  char* la1 = As + c1 * 16;
  char* lb0 = Bs + c0 * 16;
  char* lb1 = Bs + c1 * 16;

  // fragment read offsets (swizzled), constant across K-loop
  const int lr = lane & 15, ls = lane >> 4;
  int offA[4], offB[4];
#pragma unroll
  for (int m = 0; m < 4; ++m) {
    const int rA = wr * 64 + m * 16 + lr;
    offA[m] = ((rA * 4 + (ls ^ (rA & 3))) ^ (rA & 4)) * 16;
    const int rB = wc * 64 + m * 16 + lr;
    offB[m] = ((rB * 4 + (ls ^ (rB & 3))) ^ (rB & 4)) * 16;
  }

  v4f acc[4][4] = {};

  const int nk = K >> 5;
  for (int it = 0; it < nk; ++it) {
    load_lds16(pa0, la0);
    load_lds16(pa1, la1);
    load_lds16(pb0, lb0);
    load_lds16(pb1, lb1);
    pa0 += 64; pa1 += 64; pb0 += 64; pb1 += 64;
    __syncthreads();  // drains vmcnt before barrier -> tiles visible

    v8bf av[4], bvv[4];
#pragma unroll
    for (int m = 0; m < 4; ++m) av[m]  = *(const v8bf*)(As + offA[m]);
#pragma unroll
    for (int n = 0; n < 4; ++n) bvv[n] = *(const v8bf*)(Bs + offB[n]);
#pragma unroll
    for (int m = 0; m < 4; ++m)
#pragma unroll
      for (int n = 0; n < 4; ++n)
        acc[m][n] = __builtin_amdgcn_mfma_f32_16x16x32_bf16(av[m], bvv[n], acc[m][n], 0, 0, 0);
    __syncthreads();  // all ds_reads done before next stage overwrites
  }

  // epilogue: C/D layout col=lane&15, row=(lane>>4)*4+reg  [m89-verified]
  const int colb = n0 + wc * 64 + lr;
  const int rowb = m0 + wr * 64 + ls * 4;
#pragma unroll
  for (int n = 0; n < 4; ++n) {
    const int col = colb + n * 16;
    const float bv = bias[col];
    const bool rl = (col >= relu_from);
#pragma unroll
    for (int m = 0; m < 4; ++m) {
      const int rbase = rowb + m * 16;
#pragma unroll
      for (int j = 0; j < 4; ++j) {
        float v = acc[m][n][j] + bv;
        if (rl) v = fmaxf(v, 0.0f);
        C[(size_t)(rbase + j) * N + col] = __float2bfloat16(v);
      }
    }
  }
}

// ---------------------------------------------------------------------------
// finalize: per-row masked log-softmax (40 segs of 64), gather, entropy, value
// one wave per row
// ---------------------------------------------------------------------------

__global__ __launch_bounds__(256)
void finalize_kernel(const __hip_bfloat16* __restrict__ out3,
                     const int* __restrict__ masks,
                     const int* __restrict__ actions,
                     const float* __restrict__ Wc2,
                     const float* __restrict__ bc2,
                     float* __restrict__ out) {
  const int lane = threadIdx.x & 63;
  const int r = blockIdx.x * 4 + (threadIdx.x >> 6);
  const __hip_bfloat16* row = out3 + (size_t)r * 3072;
  const int* mrow = masks + (size_t)r * 2560;
  const int* arow = actions + r * 40;

  float lp_sum = 0.f, ent_sum = 0.f;
  for (int seg = 0; seg < 40; ++seg) {
    float v = __bfloat162float(row[seg * 64 + lane]);
    const int mk = mrow[seg * 64 + lane];
    v = mk ? v : -1.0e9f;
    float mx = v;
#pragma unroll
    for (int o = 32; o > 0; o >>= 1) mx = fmaxf(mx, __shfl_xor(mx, o));
    const float e = __expf(v - mx);
    float s = e, sv = e * v;
#pragma unroll
    for (int o = 32; o > 0; o >>= 1) { s += __shfl_xor(s, o); sv += __shfl_xor(sv, o); }
    const float logZ = __logf(s) + mx;
    const int act = arow[seg];
    const float va = __shfl(v, act & 63);
    if ((unsigned)act < 64u) {
      lp_sum += va - logZ;             // log-prob of chosen action
      ent_sum += logZ - sv / s;        // -sum p*logp
    } else {
      lp_sum += -1000.0f;
    }
  }

  // critic: v = relu(c1) dot Wc2 + bc2   (relu already applied in GEMM3 epilogue)
  float acc = 0.f;
#pragma unroll
  for (int i = 0; i < 8; ++i)
    acc += __bfloat162float(row[2560 + lane + i * 64]) * Wc2[lane + i * 64];
#pragma unroll
  for (int o = 32; o > 0; o >>= 1) acc += __shfl_xor(acc, o);

  if (lane == 0) {
    out[r]          = lp_sum;
    out[8192 + r]   = ent_sum;
    out[16384 + r]  = acc + bc2[0];
  }
}

// ---------------------------------------------------------------------------

extern "C" void kernel_launch(void* const* d_in, const int* in_sizes, int n_in,
                              void* d_out, int out_size, void* d_ws, size_t ws_size,
                              hipStream_t stream) {
  const float* obs    = (const float*)d_in[0];
  const int*   actions= (const int*)d_in[1];
  const int*   masks  = (const int*)d_in[2];
  const float* W1     = (const float*)d_in[3];
  const float* b1     = (const float*)d_in[4];
  const float* W2     = (const float*)d_in[5];
  const float* b2     = (const float*)d_in[6];
  const float* headsW = (const float*)d_in[7];
  const float* headsb = (const float*)d_in[8];
  const float* Wc1    = (const float*)d_in[9];
  const float* bc1    = (const float*)d_in[10];
  const float* Wc2    = (const float*)d_in[11];
  const float* bc2    = (const float*)d_in[12];
  float* out = (float*)d_out;

  char* ws = (char*)d_ws;
  __hip_bfloat16* obsB  = (__hip_bfloat16*)(ws);              // 8192*512*2   = 8388608
  __hip_bfloat16* W1t   = (__hip_bfloat16*)(ws + 8388608);    // 1024*512*2   = 1048576
  __hip_bfloat16* W2t   = (__hip_bfloat16*)(ws + 9437184);    // 1024*1024*2  = 2097152
  __hip_bfloat16* Wbigt = (__hip_bfloat16*)(ws + 11534336);   // 3072*1024*2  = 6291456
  float*          biasc = (float*)(ws + 17825792);            // 3072*4       = 12288
  __hip_bfloat16* h1    = (__hip_bfloat16*)(ws + 17838080);   // 8192*1024*2  = 16777216
  __hip_bfloat16* h2    = (__hip_bfloat16*)(ws + 34615296);   // 8192*1024*2  = 16777216
  __hip_bfloat16* out3  = (__hip_bfloat16*)(ws + 51392512);   // 8192*3072*2  = 50331648
  // total ws use: 101,724,160 bytes

  // prep: bf16 conversion + N-major weight transposes
  convert_obs<<<2048, 256, 0, stream>>>((const float4*)obs, (int4*)obsB, 524288);
  build_bias<<<12, 256, 0, stream>>>(headsb, bc1, biasc);
  transpose_to_bf16<<<dim3(32, 16, 1), dim3(32, 8), 0, stream>>>(W1, W1t, 512, 1024);
  transpose_to_bf16<<<dim3(32, 32, 1), dim3(32, 8), 0, stream>>>(W2, W2t, 1024, 1024);
  // heads: per n, [1024][320] -> [320][1024] at Wbigt + n*320*1024  (einsum permute folded in)
  transpose_to_bf16<<<dim3(10, 32, 8), dim3(32, 8), 0, stream>>>(headsW, Wbigt, 1024, 320);
  transpose_to_bf16<<<dim3(16, 32, 1), dim3(32, 8), 0, stream>>>(Wc1, Wbigt + 2560 * 1024, 1024, 512);

  // encoder + fused heads/critic GEMMs
  gemm_bf16_tn<<<dim3(8, 64), 256, 0, stream>>>(obsB, W1t, b1, h1, 8192, 1024, 512, 0);
  gemm_bf16_tn<<<dim3(8, 64), 256, 0, stream>>>(h1, W2t, b2, h2, 8192, 1024, 1024, 0);
  gemm_bf16_tn<<<dim3(24, 64), 256, 0, stream>>>(h2, Wbigt, biasc, out3, 8192, 3072, 1024, 2560);

  // masked softmax / gather / entropy / value
  finalize_kernel<<<2048, 256, 0, stream>>>(out3, masks, actions, Wc2, bc2, out);
}

// Round 2
// 154.291 us; speedup vs baseline: 1.3430x; 1.3430x over previous
//
#include <hip/hip_runtime.h>
#include <hip/hip_bf16.h>
#include <stdint.h>

// ---------------------------------------------------------------------------
// MaskedPolicy: obs->MLP->heads (masked log-softmax, gather, entropy) + critic
// B=8192 OBS=512 HID=1024 N*SUM=2560 (+512 critic cols = 3072 fused GEMM3)
// ---------------------------------------------------------------------------

typedef __bf16 v8bf __attribute__((ext_vector_type(8)));
typedef float  v4f  __attribute__((ext_vector_type(4)));

__device__ __forceinline__ void load_lds16(const void* g, void* l) {
  auto gp = (const __attribute__((address_space(1))) char*)(uintptr_t)g;
  auto lp = (__attribute__((address_space(3))) char*)(uintptr_t)l;
  __builtin_amdgcn_global_load_lds(gp, lp, 16, 0, 0);
}

// ---------------------------------------------------------------------------
// prep kernels
// ---------------------------------------------------------------------------

__global__ void convert_obs(const float4* __restrict__ in, int4* __restrict__ out, int n8) {
  const int i = blockIdx.x * blockDim.x + threadIdx.x;
  if (i >= n8) return;
  const float4 x = in[i * 2], y = in[i * 2 + 1];
  union { __hip_bfloat16 h[8]; int4 v; } u;
  u.h[0] = __float2bfloat16(x.x);
  u.h[1] = __float2bfloat16(x.y);
  u.h[2] = __float2bfloat16(x.z);
  u.h[3] = __float2bfloat16(x.w);
  u.h[4] = __float2bfloat16(y.x);
  u.h[5] = __float2bfloat16(y.y);
  u.h[6] = __float2bfloat16(y.z);
  u.h[7] = __float2bfloat16(y.w);
  out[i] = u.v;
}

__global__ void build_bias(const float* __restrict__ headsb, const float* __restrict__ bc1,
                           float* __restrict__ biasc) {
  const int i = blockIdx.x * blockDim.x + threadIdx.x;
  if (i < 2560) biasc[i] = headsb[i];
  else if (i < 3072) biasc[i] = bc1[i - 2560];
}

// [R][C] f32  ->  [C][R] bf16   (R,C multiples of 32; batched via z)
__global__ void transpose_to_bf16(const float* __restrict__ in, __hip_bfloat16* __restrict__ out,
                                  int R, int C) {
  __shared__ float t[32][33];
  const int bx = blockIdx.x * 32, by = blockIdx.y * 32;
  in  += (size_t)blockIdx.z * R * C;
  out += (size_t)blockIdx.z * R * C;
  const int x = threadIdx.x, y = threadIdx.y;
#pragma unroll
  for (int i = 0; i < 32; i += 8)
    t[y + i][x] = in[(size_t)(by + y + i) * C + bx + x];
  __syncthreads();
#pragma unroll
  for (int i = 0; i < 32; i += 8)
    out[(size_t)(bx + y + i) * R + by + x] = __float2bfloat16(t[x][y + i]);
}

// ---------------------------------------------------------------------------
// GEMM: C[M][N] = relu?(A[M][K](bf16) * Bt[N][K](bf16)^T + bias[N]) -> bf16
// 128x128 tile, BK=32, 4 waves (2x2), mfma_f32_16x16x32_bf16, global_load_lds,
// bank-conflict-free chunk swizzle c(r,s) = (4r + (s^(r&3))) ^ (r&4).
// ---------------------------------------------------------------------------

__global__ __launch_bounds__(256, 2)
void gemm_bf16_tn(const __hip_bfloat16* __restrict__ A,
                  const __hip_bfloat16* __restrict__ Bt,
                  const float* __restrict__ bias,
                  __hip_bfloat16* __restrict__ C,
                  int M, int N, int K, int relu_from) {
  __shared__ char As[8192];
  __shared__ char Bs[8192];
  const int tid  = threadIdx.x;
  const int lane = tid & 63;
  const int wave = tid >> 6;
  const int wr = wave >> 1, wc = wave & 1;
  const int m0 = blockIdx.y * 128, n0 = blockIdx.x * 128;

  const int c0 = tid, c1 = tid + 256;
  const int r0 = ((c0 >> 3) << 1) | (((c0 >> 2) ^ (c0 >> 4)) & 1);
  const int s0 = (c0 & 3) ^ (r0 & 3);
  const int r1 = ((c1 >> 3) << 1) | (((c1 >> 2) ^ (c1 >> 4)) & 1);
  const int s1 = (c1 & 3) ^ (r1 & 3);

  const char* pa0 = (const char*)A  + ((size_t)(m0 + r0) * K) * 2 + s0 * 16;
  const char* pa1 = (const char*)A  + ((size_t)(m0 + r1) * K) * 2 + s1 * 16;
  const char* pb0 = (const char*)Bt + ((size_t)(n0 + r0) * K) * 2 + s0 * 16;
  const char* pb1 = (const char*)Bt + ((size_t)(n0 + r1) * K) * 2 + s1 * 16;

  char* la0 = As + c0 * 16;
  char* la1 = As + c1 * 16;
  char* lb0 = Bs + c0 * 16;
  char* lb1 = Bs + c1 * 16;

  const int lr = lane & 15, ls = lane >> 4;
  int offA[4], offB[4];
#pragma unroll
  for (int m = 0; m < 4; ++m) {
    const int rA = wr * 64 + m * 16 + lr;
    offA[m] = ((rA * 4 + (ls ^ (rA & 3))) ^ (rA & 4)) * 16;
    const int rB = wc * 64 + m * 16 + lr;
    offB[m] = ((rB * 4 + (ls ^ (rB & 3))) ^ (rB & 4)) * 16;
  }

  v4f acc[4][4] = {};

  const int nk = K >> 5;
  for (int it = 0; it < nk; ++it) {
    load_lds16(pa0, la0);
    load_lds16(pa1, la1);
    load_lds16(pb0, lb0);
    load_lds16(pb1, lb1);
    pa0 += 64; pa1 += 64; pb0 += 64; pb1 += 64;
    __syncthreads();

    v8bf av[4], bvv[4];
#pragma unroll
    for (int m = 0; m < 4; ++m) av[m]  = *(const v8bf*)(As + offA[m]);
#pragma unroll
    for (int n = 0; n < 4; ++n) bvv[n] = *(const v8bf*)(Bs + offB[n]);
#pragma unroll
    for (int m = 0; m < 4; ++m)
#pragma unroll
      for (int n = 0; n < 4; ++n)
        acc[m][n] = __builtin_amdgcn_mfma_f32_16x16x32_bf16(av[m], bvv[n], acc[m][n], 0, 0, 0);
    __syncthreads();
  }

  const int colb = n0 + wc * 64 + lr;
  const int rowb = m0 + wr * 64 + ls * 4;
#pragma unroll
  for (int n = 0; n < 4; ++n) {
    const int col = colb + n * 16;
    const float bv = bias[col];
    const bool rl = (col >= relu_from);
#pragma unroll
    for (int m = 0; m < 4; ++m) {
      const int rbase = rowb + m * 16;
#pragma unroll
      for (int j = 0; j < 4; ++j) {
        float v = acc[m][n][j] + bv;
        if (rl) v = fmaxf(v, 0.0f);
        C[(size_t)(rbase + j) * N + col] = __float2bfloat16(v);
      }
    }
  }
}

// ---------------------------------------------------------------------------
// finalize v2: one wave per row; per pass, 8 segments in parallel
// (8-lane group per segment, 8 elems per lane, vectorized 16B/32B loads).
// 5 passes of 3-step shuffle reduces instead of 40 passes of 6-step.
// ---------------------------------------------------------------------------

__global__ __launch_bounds__(256)
void finalize_kernel(const __hip_bfloat16* __restrict__ out3,
                     const int* __restrict__ masks,
                     const int* __restrict__ actions,
                     const float* __restrict__ Wc2,
                     const float* __restrict__ bc2,
                     float* __restrict__ out) {
  const int lane = threadIdx.x & 63;
  const int r = blockIdx.x * 4 + (threadIdx.x >> 6);
  const __hip_bfloat16* row = out3 + (size_t)r * 3072;
  const int* mrow = masks + (size_t)r * 2560;
  const int* arow = actions + r * 40;

  const int g = lane >> 3;   // segment group within wave
  const int gl = lane & 7;   // lane within group

  float lp_sum = 0.f, ent_sum = 0.f;

#pragma unroll
  for (int p = 0; p < 5; ++p) {
    const int base = p * 512 + lane * 8;           // element idx within 2560
    union { int4 q; __hip_bfloat16 h[8]; } u;
    u.q = *(const int4*)(row + base);
    const int4 ma = *(const int4*)(mrow + base);
    const int4 mb = *(const int4*)(mrow + base + 4);

    float v[8];
    v[0] = ma.x ? __bfloat162float(u.h[0]) : -1.0e9f;
    v[1] = ma.y ? __bfloat162float(u.h[1]) : -1.0e9f;
    v[2] = ma.z ? __bfloat162float(u.h[2]) : -1.0e9f;
    v[3] = ma.w ? __bfloat162float(u.h[3]) : -1.0e9f;
    v[4] = mb.x ? __bfloat162float(u.h[4]) : -1.0e9f;
    v[5] = mb.y ? __bfloat162float(u.h[5]) : -1.0e9f;
    v[6] = mb.z ? __bfloat162float(u.h[6]) : -1.0e9f;
    v[7] = mb.w ? __bfloat162float(u.h[7]) : -1.0e9f;

    // segment max: local 8-tree then 3-step group reduce
    float mx = fmaxf(fmaxf(fmaxf(v[0], v[1]), fmaxf(v[2], v[3])),
                     fmaxf(fmaxf(v[4], v[5]), fmaxf(v[6], v[7])));
#pragma unroll
    for (int o = 1; o < 8; o <<= 1) mx = fmaxf(mx, __shfl_xor(mx, o));

    float s = 0.f, sv = 0.f;
#pragma unroll
    for (int j = 0; j < 8; ++j) {
      const float e = __expf(v[j] - mx);
      s += e;
      sv += e * v[j];
    }
#pragma unroll
    for (int o = 1; o < 8; o <<= 1) { s += __shfl_xor(s, o); sv += __shfl_xor(sv, o); }

    const float logZ = __logf(s) + mx;

    const int act = arow[p * 8 + g];
    // select v[act&7] without runtime array indexing (avoid scratch)
    float va_loc = v[0];
#pragma unroll
    for (int j = 1; j < 8; ++j) va_loc = ((act & 7) == j) ? v[j] : va_loc;
    const float va = __shfl(va_loc, (lane & 56) | ((act >> 3) & 7));

    if ((unsigned)act < 64u) {
      lp_sum += va - logZ;
      ent_sum += logZ - sv / s;
    } else {
      lp_sum += -1000.0f;
    }
  }

  // lanes within a group hold identical sums; reduce across the 8 groups
#pragma unroll
  for (int o = 8; o < 64; o <<= 1) {
    lp_sum += __shfl_xor(lp_sum, o);
    ent_sum += __shfl_xor(ent_sum, o);
  }

  // critic: relu(c1) (already relu'd, bf16) dot Wc2 + bc2
  union { int4 q; __hip_bfloat16 h[8]; } c;
  c.q = *(const int4*)(row + 2560 + lane * 8);
  const float4 w0 = *(const float4*)(Wc2 + lane * 8);
  const float4 w1 = *(const float4*)(Wc2 + lane * 8 + 4);
  float acc = __bfloat162float(c.h[0]) * w0.x + __bfloat162float(c.h[1]) * w0.y +
              __bfloat162float(c.h[2]) * w0.z + __bfloat162float(c.h[3]) * w0.w +
              __bfloat162float(c.h[4]) * w1.x + __bfloat162float(c.h[5]) * w1.y +
              __bfloat162float(c.h[6]) * w1.z + __bfloat162float(c.h[7]) * w1.w;
#pragma unroll
  for (int o = 32; o > 0; o >>= 1) acc += __shfl_xor(acc, o);

  if (lane == 0) {
    out[r]         = lp_sum;
    out[8192 + r]  = ent_sum;
    out[16384 + r] = acc + bc2[0];
  }
}

// ---------------------------------------------------------------------------

extern "C" void kernel_launch(void* const* d_in, const int* in_sizes, int n_in,
                              void* d_out, int out_size, void* d_ws, size_t ws_size,
                              hipStream_t stream) {
  const float* obs    = (const float*)d_in[0];
  const int*   actions= (const int*)d_in[1];
  const int*   masks  = (const int*)d_in[2];
  const float* W1     = (const float*)d_in[3];
  const float* b1     = (const float*)d_in[4];
  const float* W2     = (const float*)d_in[5];
  const float* b2     = (const float*)d_in[6];
  const float* headsW = (const float*)d_in[7];
  const float* headsb = (const float*)d_in[8];
  const float* Wc1    = (const float*)d_in[9];
  const float* bc1    = (const float*)d_in[10];
  const float* Wc2    = (const float*)d_in[11];
  const float* bc2    = (const float*)d_in[12];
  float* out = (float*)d_out;

  char* ws = (char*)d_ws;
  __hip_bfloat16* obsB  = (__hip_bfloat16*)(ws);              // 8192*512*2   = 8388608
  __hip_bfloat16* W1t   = (__hip_bfloat16*)(ws + 8388608);    // 1024*512*2   = 1048576
  __hip_bfloat16* W2t   = (__hip_bfloat16*)(ws + 9437184);    // 1024*1024*2  = 2097152
  __hip_bfloat16* Wbigt = (__hip_bfloat16*)(ws + 11534336);   // 3072*1024*2  = 6291456
  float*          biasc = (float*)(ws + 17825792);            // 3072*4       = 12288
  __hip_bfloat16* h1    = (__hip_bfloat16*)(ws + 17838080);   // 8192*1024*2  = 16777216
  __hip_bfloat16* h2    = (__hip_bfloat16*)(ws + 34615296);   // 8192*1024*2  = 16777216
  __hip_bfloat16* out3  = (__hip_bfloat16*)(ws + 51392512);   // 8192*3072*2  = 50331648

  convert_obs<<<2048, 256, 0, stream>>>((const float4*)obs, (int4*)obsB, 524288);
  build_bias<<<12, 256, 0, stream>>>(headsb, bc1, biasc);
  transpose_to_bf16<<<dim3(32, 16, 1), dim3(32, 8), 0, stream>>>(W1, W1t, 512, 1024);
  transpose_to_bf16<<<dim3(32, 32, 1), dim3(32, 8), 0, stream>>>(W2, W2t, 1024, 1024);
  transpose_to_bf16<<<dim3(10, 32, 8), dim3(32, 8), 0, stream>>>(headsW, Wbigt, 1024, 320);
  transpose_to_bf16<<<dim3(16, 32, 1), dim3(32, 8), 0, stream>>>(Wc1, Wbigt + 2560 * 1024, 1024, 512);

  gemm_bf16_tn<<<dim3(8, 64), 256, 0, stream>>>(obsB, W1t, b1, h1, 8192, 1024, 512, 0);
  gemm_bf16_tn<<<dim3(8, 64), 256, 0, stream>>>(h1, W2t, b2, h2, 8192, 1024, 1024, 0);
  gemm_bf16_tn<<<dim3(24, 64), 256, 0, stream>>>(h2, Wbigt, biasc, out3, 8192, 3072, 1024, 2560);

  finalize_kernel<<<2048, 256, 0, stream>>>(out3, masks, actions, Wc2, bc2, out);
}